// Round 7
// baseline (230.069 us; speedup 1.0000x reference)
//
#include <hip/hip_runtime.h>

// NCC forces, 192^3 fp32. Round 7: R6 with DPP direction FIXED.
// (GCN DPP semantics: row_shr:N = dest lane i <- src lane i-N;
//  row_shl:N = dest lane i <- src lane i+N. R6 had them swapped ->
//  negated interior x-gradient, absmax 5.96e-2.)
//  - ZSEG 16: 1728 blocks x 21 iters (vs R5 2304 x 17) = -7.4% block-iters.
//  - x-gradient neighbors via DPP on the register center ring; tx=0/15 edge
//    lanes patch from LDS halo (also covers DPP row-boundary invalid lanes).
//  - else identical to R5: XCD swizzle, float4 pipelined staging, reg x-sum
//    sliding, chunk-8 y-phase, box ping-pong, NT mask loads, plain stores.

#define DD 192
#define HH 192
#define WW 192
#define NVOX (DD * HH * WW)
#define TS 16
#define RR 20            // staged rows (y: y0-2 .. y0+17)
#define RW 24            // staged row width (x: x0-4 .. x0+19)
#define ZSEG 16
#define NBX 12
#define NBY 12
#define NBZ 12           // 192/16
#define PER_XCD ((NBX * NBY * NBZ) / 8)   // 216

__device__ __forceinline__ float dpp_xm1(float v) {   // dest lane i = src lane i-1 (tx-1): row_shr:1
    int r = __builtin_amdgcn_update_dpp(__float_as_int(v), __float_as_int(v),
                                        0x111, 0xF, 0xF, true);
    return __int_as_float(r);
}
__device__ __forceinline__ float dpp_xp1(float v) {   // dest lane i = src lane i+1 (tx+1): row_shl:1
    int r = __builtin_amdgcn_update_dpp(__float_as_int(v), __float_as_int(v),
                                        0x101, 0xF, 0xF, true);
    return __int_as_float(r);
}

__global__ __launch_bounds__(256)
void ncc_forces_kernel(const float* __restrict__ mimg,
                       const float* __restrict__ fimg,
                       const int*   __restrict__ mmask,
                       const int*   __restrict__ fmask,
                       float* __restrict__ out)
{
    __shared__ float rawm[5][RR][RW];     // 9600 B
    __shared__ float rawf[5][RR][RW];     // 9600 B
    __shared__ float xs[5][RR][20];       // 8000 B  [field][yrow][xo]
    __shared__ float box[2][5][TS][20];   // 12800 B [pp][field][x][yout]  => 40000 B

    // XCD swizzle: XCD k gets 216 consecutive logical blocks (z-slab locality)
    const int b  = blockIdx.x;
    const int L  = (b & 7) * PER_XCD + (b >> 3);
    const int bz = L / (NBX * NBY);
    const int r_ = L - bz * (NBX * NBY);
    const int by = r_ / NBX;
    const int bx = r_ - by * NBX;

    const int tid = threadIdx.x;
    const int tx = tid & 15, ty = tid >> 4;
    const int x0 = bx * TS, y0 = by * TS, z0 = bz * ZSEG;

    // ---- staging roles: 240 lanes = 2 images x 20 rows x 6 quads ----
    const int  simg   = tid / 120;            // 0,1 stager; 2 idle
    const bool stager = (simg < 2);
    const int  st     = tid - simg * 120;
    const int  srow   = st / 6;
    const int  squad  = st - srow * 6;
    const int  sgy    = y0 - 2 + srow;
    const int  sgx    = x0 - 4 + 4 * squad;
    const bool sin_   = (sgy >= 0) && (sgy < HH) && (sgx >= 0) && (sgx <= WW - 4);
    const float* sptr = (simg == 1) ? fimg : mimg;
    float* sldsb = (simg == 1) ? &rawf[0][0][0] : &rawm[0][0][0];
    const int  sloff  = srow * RW + 4 * squad;

    float4 pref = make_float4(0, 0, 0, 0);
    auto prefetch = [&](int zz) {
        pref = make_float4(0, 0, 0, 0);
        if (stager && sin_ && zz >= 0 && zz < DD)
            pref = *(const float4*)(sptr + ((size_t)zz * HH + sgy) * WW + sgx);
    };

    // per-thread rings
    float ring[5][5];
#pragma unroll
    for (int s = 0; s < 5; ++s)
#pragma unroll
        for (int f = 0; f < 5; ++f) ring[s][f] = 0.f;
    float cm[5] = {0, 0, 0, 0, 0}, cf[5] = {0, 0, 0, 0, 0};

    prefetch(z0 - 2);

    for (int n = 0; n <= ZSEG + 4; ++n) {
        const int zc = z0 - 2 + n;           // slice committed this iter
        const int sw = n % 5;                // raw write slot
        const int z  = zc - 3;               // slice emitted this iter
        const bool emitv = (n >= 5);

        // ---- commit staged slice zc; issue loads for zc+1 ----
        if (stager) *(float4*)(sldsb + sw * (RR * RW) + sloff) = pref;
        prefetch(zc + 1);

        int um = 0, uf = 0;
        int vidx = 0;
        if (emitv) {
            vidx = (z * HH + (y0 + ty)) * WW + (x0 + tx);
            um = __builtin_nontemporal_load(mmask + vidx);
            uf = __builtin_nontemporal_load(fmask + vidx);
        }

        __syncthreads();   // A: raw[sw] ready; box[(n-1)&1] ready

        // ---- x-phase: 80 chunk-of-4 tasks, vector LDS IO ----
        if (tid < 80) {
            const int yy = tid >> 2;          // 0..19
            const int t4 = (tid & 3) * 4;     // 0,4,8,12
            const float4 A0 = *(const float4*)&rawm[sw][yy][t4];
            const float4 A1 = *(const float4*)&rawm[sw][yy][t4 + 4];
            const float2 A2 = *(const float2*)&rawm[sw][yy][t4 + 8];
            const float4 B0 = *(const float4*)&rawf[sw][yy][t4];
            const float4 B1 = *(const float4*)&rawf[sw][yy][t4 + 4];
            const float2 B2 = *(const float2*)&rawf[sw][yy][t4 + 8];
            const float a[10] = {A0.x, A0.y, A0.z, A0.w, A1.x, A1.y, A1.z, A1.w, A2.x, A2.y};
            const float bb[10] = {B0.x, B0.y, B0.z, B0.w, B1.x, B1.y, B1.z, B1.w, B2.x, B2.y};
            float p[10], s, w0, w1, w2, w3;
#pragma unroll
            for (int f = 0; f < 5; ++f) {
#pragma unroll
                for (int i = 2; i < 10; ++i) {
                    p[i] = (f == 0) ? a[i] : (f == 1) ? bb[i] :
                           (f == 2) ? a[i] * a[i] : (f == 3) ? bb[i] * bb[i] : a[i] * bb[i];
                }
                s = p[2] + p[3] + p[4] + p[5] + p[6]; w0 = s;
                s += p[7] - p[2]; w1 = s;
                s += p[8] - p[3]; w2 = s;
                s += p[9] - p[4]; w3 = s;
                *(float4*)&xs[f][yy][t4] = make_float4(w0, w1, w2, w3);
            }
        }

        // centers: fresh slice zc -> register ring
        {
            const float ncm = rawm[sw][ty + 2][tx + 4];
            const float ncf = rawf[sw][ty + 2][tx + 4];
#pragma unroll
            for (int s2 = 4; s2 > 0; --s2) { cm[s2] = cm[s2 - 1]; cf[s2] = cf[s2 - 1]; }
            cm[0] = ncm; cf[0] = ncf;
        }
        // this slice's 2D sums (from iter n-1's y-phase) -> shift ring
        if (n >= 1) {
            const int pp = (n - 1) & 1;
            float s2d[5];
#pragma unroll
            for (int f = 0; f < 5; ++f) s2d[f] = box[pp][f][tx][ty];
#pragma unroll
            for (int s = 0; s < 4; ++s)
#pragma unroll
                for (int f = 0; f < 5; ++f) ring[s][f] = ring[s + 1][f];
#pragma unroll
            for (int f = 0; f < 5; ++f) ring[4][f] = s2d[f];
        }

        if (emitv) {
            float sum_m = 0.f, sum_f = 0.f, sum_mm = 0.f, sum_ff = 0.f, sum_mf = 0.f;
#pragma unroll
            for (int s = 0; s < 5; ++s) {
                sum_m  += ring[s][0];
                sum_f  += ring[s][1];
                sum_mm += ring[s][2];
                sum_ff += ring[s][3];
                sum_mf += ring[s][4];
            }
            const int gx = x0 + tx, gy = y0 + ty;
            const int s2 = (n + 2) % 5;       // slot of slice z (= zc-3)
            const int cy = ty + 2, cx = tx + 4;
            const float mc = cm[3];           // center at z
            const float fc = cf[3];

            // x-neighbors via DPP (tx spans one 16-lane DPP row); edges from LDS
            float mxm = dpp_xm1(mc), mxp = dpp_xp1(mc);
            float fxm = dpp_xm1(fc), fxp = dpp_xp1(fc);
            if (tx == 0)       { mxm = rawm[s2][cy][3];  fxm = rawf[s2][cy][3]; }
            else if (tx == 15) { mxp = rawm[s2][cy][20]; fxp = rawf[s2][cy][20]; }

            float gxm, gxf, gym, gyf, gzm, gzf;
            if (gx == 0)          { gxm = mxp - mc;  gxf = fxp - fc; }
            else if (gx == WW-1)  { gxm = mc - mxm;  gxf = fc - fxm; }
            else                  { gxm = 0.5f * (mxp - mxm); gxf = 0.5f * (fxp - fxm); }

            if (gy == 0)          { gym = rawm[s2][cy + 1][cx] - mc;  gyf = rawf[s2][cy + 1][cx] - fc; }
            else if (gy == HH-1)  { gym = mc - rawm[s2][cy - 1][cx];  gyf = fc - rawf[s2][cy - 1][cx]; }
            else {
                gym = 0.5f * (rawm[s2][cy + 1][cx] - rawm[s2][cy - 1][cx]);
                gyf = 0.5f * (rawf[s2][cy + 1][cx] - rawf[s2][cy - 1][cx]);
            }
            if (z == 0)           { gzm = cm[2] - mc;             gzf = cf[2] - fc; }
            else if (z == DD-1)   { gzm = mc - cm[4];             gzf = fc - cf[4]; }
            else                  { gzm = 0.5f * (cm[2] - cm[4]); gzf = 0.5f * (cf[2] - cf[4]); }

            const float u = ((um != 0) || (uf != 0)) ? 1.0f : 0.0f;

            const float npix = 125.0f;
            const float inv_npix = 1.0f / 125.0f;
            const float mean_m = sum_m * inv_npix;
            const float mean_f = sum_f * inv_npix;
            const float var_m = sum_mm - 2.0f * mean_m * sum_m + npix * mean_m * mean_m;
            const float var_f = sum_ff - 2.0f * mean_f * sum_f + npix * mean_f * mean_f;
            const float var_mf = var_m * var_f;
            const float cross = sum_mf - mean_f * sum_m - mean_m * sum_f + npix * mean_m * mean_f;
            const float mmc = mc - mean_m;
            const float fmc = fc - mean_f;
            const bool ok = (var_mf > 1e-5f) && (var_f > 1e-5f) && (fmc != 0.0f) && (mmc != 0.0f);
            float factor = 0.0f;
            if (ok) factor = 2.0f * cross / var_mf * (mmc - cross * fmc / var_f);

            const float nf = -factor * 0.5f * u;
            out[vidx]            = nf * (gzm + gzf);   // ch 0: d/dD
            out[NVOX + vidx]     = nf * (gym + gyf);   // ch 1: d/dH
            out[2 * NVOX + vidx] = nf * (gxm + gxf);   // ch 2: d/dW
        }

        __syncthreads();   // B: xs ready (and emit reads of box/raw done)

        // ---- y-phase: 160 chunk-of-8 sliding tasks -> box[n&1] ----
        if (tid < 160) {
            const int x  = tid & 15;
            const int c8 = ((tid >> 4) & 1) * 8;   // 0 or 8
            const int f  = tid >> 5;               // 0..4
            float v[12];
#pragma unroll
            for (int j = 0; j < 12; ++j) v[j] = xs[f][c8 + j][x];
            float o[8];
            float s = v[0] + v[1] + v[2] + v[3] + v[4];
            o[0] = s;
#pragma unroll
            for (int j = 1; j < 8; ++j) { s += v[j + 4] - v[j - 1]; o[j] = s; }
            float* bp = &box[n & 1][f][x][c8];
            *(float4*)bp       = make_float4(o[0], o[1], o[2], o[3]);
            *(float4*)(bp + 4) = make_float4(o[4], o[5], o[6], o[7]);
        }
        // no trailing barrier:
        //  - next commit writes raw[(n+1)%5]; readers this iter used {n, n+2}%5.
        //  - next x-phase (writes xs) is fenced by next barrier A.
        //  - box[n&1] is read at emit(n+1) after A(n+1), rewritten at y(n+2).
    }
}

extern "C" void kernel_launch(void* const* d_in, const int* in_sizes, int n_in,
                              void* d_out, int out_size, void* d_ws, size_t ws_size,
                              hipStream_t stream)
{
    const float* mimg  = (const float*)d_in[0];
    const float* fimg  = (const float*)d_in[1];
    const int*   mmask = (const int*)d_in[2];
    const int*   fmask = (const int*)d_in[3];
    float* out = (float*)d_out;

    dim3 grid(NBX * NBY * NBZ, 1, 1);   // 1728 blocks
    dim3 block(256, 1, 1);
    hipLaunchKernelGGL(ncc_forces_kernel, grid, block, 0, stream,
                       mimg, fimg, mmask, fmask, out);
}